// Round 11
// baseline (1955.177 us; speedup 1.0000x reference)
//
#include <hip/hip_runtime.h>

#define NN 100000
#define NE 1600000
#define NG 128
#define DIN 20
#define DEMB 300
#define DHID 600
#define DOUT 64
// padded dims
#define DIN_P 32
#define EMB_P 320   // activation storage width (multiple of 64)
#define HID_P 640
#define EMB_G 384   // bias/stats row padding
#define SCAN_BLK 392  // ceil(NN/256)
#define MT128 782     // ceil(NN/128) (fat gemm2 M-tiles)
#define PT_LD 784     // partT column stride

static const float BN_EPS_F = 1e-5f;

typedef _Float16 f16x8 __attribute__((ext_vector_type(8)));
typedef float f32x4 __attribute__((ext_vector_type(4)));

// async global->LDS, 16B per lane; LDS dst = wave-uniform base + lane*16
__device__ __forceinline__ void gload_lds16(const void* g, const void* l) {
  __builtin_amdgcn_global_load_lds(
      (const __attribute__((address_space(1))) unsigned int*)(unsigned long long)g,
      (__attribute__((address_space(3))) unsigned int*)(unsigned long long)(unsigned int)(unsigned long long)l,
      16, 0, 0);
}

// ---------------- CSR build: ONE atomic pass (packed u64: count | biased fixed-point esum) ----

__global__ void pass1_kernel(const int* __restrict__ dst, const float* __restrict__ ef,
                             unsigned long long* __restrict__ packed, unsigned* __restrict__ ord) {
  int e = blockIdx.x * blockDim.x + threadIdx.x;
  if (e >= NE) return;
  int v = dst[e];
  long long fx = (long long)llrintf(ef[e] * 16777216.0f) + (1ll << 28);
  unsigned long long add = (1ull << 44) | (unsigned long long)fx;
  unsigned long long old = atomicAdd(&packed[v], add);
  ord[e] = (unsigned)(old >> 44);
}

__global__ __launch_bounds__(256) void scan_part1(const unsigned long long* __restrict__ packed,
                                                  int* __restrict__ bsums) {
  __shared__ int red[256];
  int t = threadIdx.x;
  int i = blockIdx.x * 256 + t;
  red[t] = (i < NN) ? (int)(packed[i] >> 44) : 0;
  __syncthreads();
  for (int s = 128; s > 0; s >>= 1) {
    if (t < s) red[t] += red[t + s];
    __syncthreads();
  }
  if (t == 0) bsums[blockIdx.x] = red[0];
}

// part3: block offset from bsums; writes row_ptr AND decodes esum
__global__ __launch_bounds__(256) void scan_part3(const unsigned long long* __restrict__ packed,
                                                  const int* __restrict__ bsums,
                                                  int* __restrict__ row_ptr,
                                                  float* __restrict__ esum) {
  __shared__ int sc[256];
  __shared__ int bo;
  int t = threadIdx.x;
  int i = blockIdx.x * 256 + t;
  int pb = 0;
  for (int k = t; k < SCAN_BLK; k += 256)
    if (k < blockIdx.x) pb += bsums[k];
  sc[t] = pb;
  __syncthreads();
  for (int s = 128; s > 0; s >>= 1) {
    if (t < s) sc[t] += sc[t + s];
    __syncthreads();
  }
  if (t == 0) bo = sc[0];
  __syncthreads();
  int v = 0;
  float es = 0.f;
  if (i < NN) {
    unsigned long long p = packed[i];
    v = (int)(p >> 44);
    long long low = (long long)(p & ((1ull << 44) - 1));
    es = (float)(low - ((long long)v << 28)) * (1.f / 16777216.f);
  }
  sc[t] = v;
  __syncthreads();
  for (int off = 1; off < 256; off <<= 1) {
    int u = (t >= off) ? sc[t - off] : 0;
    __syncthreads();
    sc[t] += u;
    __syncthreads();
  }
  if (i < NN) {
    row_ptr[i] = sc[t] - v + bo;
    esum[i] = es;
  }
  if (i == NN - 1) row_ptr[NN] = NE;
}

// no atomics: final placement via row_ptr + precomputed ordinal
__global__ void place_kernel(const int* __restrict__ src, const int* __restrict__ dst,
                             const int* __restrict__ row_ptr, const unsigned* __restrict__ ord,
                             int* __restrict__ csr_src) {
  int e = blockIdx.x * blockDim.x + threadIdx.x;
  if (e >= NE) return;
  csr_src[row_ptr[dst[e]] + (int)ord[e]] = src[e];
}

// ---------------- pad node_feats fp32 [N][20] -> fp32 [N][32] (one aligned line/row) ----

__global__ void pad_nf_kernel(const float* __restrict__ nf, float* __restrict__ x32) {
  int idx = blockIdx.x * blockDim.x + threadIdx.x;
  if (idx >= NN * 32) return;
  int row = idx >> 5, c = idx & 31;
  x32[idx] = (c < DIN) ? nf[row * DIN + c] : 0.f;
}

// ---------------- ONE fused repack kernel: all weights + biases ----------------

#define RT0 (HID_P * DIN_P)                 // 20480
#define RT1 (RT0 + 4 * HID_P * EMB_P)       // 839680
#define RT2 (RT1 + 5 * EMB_G * HID_P)       // 2068480
#define RT3 (RT2 + 5 * HID_P)               // 2071680
#define RT4 (RT3 + 5 * EMB_G)               // 2073600

__global__ void repack_all_kernel(const float* __restrict__ w1_0, const float* __restrict__ w1s,
                                  const float* __restrict__ w2_0, const float* __restrict__ w2s,
                                  const float* __restrict__ b1_0, const float* __restrict__ b1s,
                                  const float* __restrict__ b2_0, const float* __restrict__ b2s,
                                  _Float16* __restrict__ w1t0, _Float16* __restrict__ w1t,
                                  _Float16* __restrict__ w2t, float* __restrict__ b1p,
                                  float* __restrict__ b2p) {
  int idx = blockIdx.x * blockDim.x + threadIdx.x;
  if (idx >= RT4) return;
  if (idx < RT0) {
    int n = idx / DIN_P, k = idx - n * DIN_P;
    float v = (n < DHID && k < DIN) ? w1_0[(size_t)k * DHID + n] : 0.f;
    w1t0[idx] = (_Float16)v;
  } else if (idx < RT1) {
    int r = idx - RT0;
    int l = r / (HID_P * EMB_P);
    int q = r - l * (HID_P * EMB_P);
    int n = q / EMB_P, k = q - n * EMB_P;
    const float* w = w1s + (size_t)l * DEMB * DHID;
    float v = (n < DHID && k < DEMB) ? w[(size_t)k * DHID + n] : 0.f;
    w1t[r] = (_Float16)v;
  } else if (idx < RT2) {
    int r = idx - RT1;
    int l = r / (EMB_G * HID_P);
    int q = r - l * (EMB_G * HID_P);
    int n = q / HID_P, k = q - n * HID_P;
    const float* w = (l == 0) ? w2_0 : w2s + (size_t)(l - 1) * DHID * DEMB;
    float v = (n < DEMB && k < DHID) ? w[(size_t)k * DEMB + n] : 0.f;
    w2t[r] = (_Float16)v;
  } else if (idx < RT3) {
    int r = idx - RT2;
    int l = r / HID_P, i = r - l * HID_P;
    const float* b = (l == 0) ? b1_0 : b1s + (size_t)(l - 1) * DHID;
    b1p[r] = (i < DHID) ? b[i] : 0.f;
  } else {
    int r = idx - RT3;
    int l = r / EMB_G, i = r - l * EMB_G;
    const float* b = (l == 0) ? b2_0 : b2s + (size_t)(l - 1) * DEMB;
    b2p[r] = (i < DEMB) ? b[i] : 0.f;
  }
}

// ---------------- layer-0 spmm: padded fp32 x[N][32] -> fp16 agg0[N][32] ----------------

__global__ __launch_bounds__(256) void spmm0_kernel(const float* __restrict__ x32,
                                                    const int* __restrict__ row_ptr,
                                                    const int* __restrict__ csr_src,
                                                    const float* __restrict__ esum,
                                                    _Float16* __restrict__ out) {
  int node = (blockIdx.x * blockDim.x + threadIdx.x) >> 5;
  int lane = threadIdx.x & 31;
  if (node >= NN) return;
  int beg = row_ptr[node], end = row_ptr[node + 1];
  float acc = 0.f;
  int nch = (end - beg + 7) >> 3;
  if (nch > 0) {
    int last = end - 1;
    float v[8];
    {
      int id[8];
#pragma unroll
      for (int u = 0; u < 8; ++u) id[u] = csr_src[min(beg + u, last)];
#pragma unroll
      for (int u = 0; u < 8; ++u) v[u] = x32[(size_t)id[u] * 32 + lane];
    }
    int cj = beg;
    for (int c = 1; c < nch; ++c) {
      int nj = beg + c * 8;
      int id[8];
#pragma unroll
      for (int u = 0; u < 8; ++u) id[u] = csr_src[min(nj + u, last)];
      float w[8];
#pragma unroll
      for (int u = 0; u < 8; ++u) w[u] = x32[(size_t)id[u] * 32 + lane];
#pragma unroll
      for (int u = 0; u < 8; ++u) acc += v[u];
#pragma unroll
      for (int u = 0; u < 8; ++u) v[u] = w[u];
      cj = nj;
    }
    int rem = end - cj;
#pragma unroll
    for (int u = 0; u < 8; ++u)
      if (u < rem) acc += v[u];
  }
  float vv = (lane < DIN) ? acc + esum[node] : 0.f;
  out[(size_t)node * DIN_P + lane] = (_Float16)vv;
}

// ---------------- fused spmm (layers 1..4): BN-finalize folded in ----------------
// split into two half-range dispatches (nbeg) so rocprof top-5 surfaces the gemms

__global__ __launch_bounds__(256) void spmm_f16_kernel(const _Float16* __restrict__ x,
                                                       const float* __restrict__ stats,
                                                       const float* __restrict__ gamma,
                                                       const float* __restrict__ beta,
                                                       const int* __restrict__ row_ptr,
                                                       const int* __restrict__ csr_src,
                                                       const float* __restrict__ esum,
                                                       _Float16* __restrict__ out,
                                                       int nbeg) {
  __shared__ float scl[EMB_P], shl[EMB_P];
  int t = threadIdx.x;
  for (int q = t; q < EMB_P; q += 256) {
    float s = 0.f, h = 0.f;
    if (q < DEMB) {
      float mu = stats[q] * (1.f / (float)NN);
      float var = fmaxf(stats[EMB_G + q] * (1.f / (float)NN) - mu * mu, 0.f);
      s = gamma[q] * rsqrtf(var + BN_EPS_F);
      h = beta[q] - mu * s;
    }
    scl[q] = s; shl[q] = h;
  }
  __syncthreads();

  int wid = nbeg + ((blockIdx.x * blockDim.x + threadIdx.x) >> 6);
  int lane = threadIdx.x & 63;
  int beg = row_ptr[wid], end = row_ptr[wid + 1];
  float deg = (float)(end - beg);
  float es = esum[wid];
  if (lane >= 40) return;
  const f16x8* xb = (const f16x8*)x;
  float acc[8] = {};
  int nch = (end - beg + 7) >> 3;
  if (nch > 0) {
    int last = end - 1;
    f16x8 v[8];
    {
      int id[8];
#pragma unroll
      for (int u = 0; u < 8; ++u) id[u] = csr_src[min(beg + u, last)];
#pragma unroll
      for (int u = 0; u < 8; ++u) v[u] = xb[(size_t)id[u] * 40 + lane];
    }
    int cj = beg;
    for (int c = 1; c < nch; ++c) {
      int nj = beg + c * 8;
      int id[8];
#pragma unroll
      for (int u = 0; u < 8; ++u) id[u] = csr_src[min(nj + u, last)];
      f16x8 w[8];
#pragma unroll
      for (int u = 0; u < 8; ++u) w[u] = xb[(size_t)id[u] * 40 + lane];
#pragma unroll
      for (int u = 0; u < 8; ++u)
#pragma unroll
        for (int i = 0; i < 8; ++i) acc[i] += (float)v[u][i];
#pragma unroll
      for (int u = 0; u < 8; ++u) v[u] = w[u];
      cj = nj;
    }
    int rem = end - cj;
#pragma unroll
    for (int u = 0; u < 8; ++u)
      if (u < rem)
#pragma unroll
        for (int i = 0; i < 8; ++i) acc[i] += (float)v[u][i];
  }
  int c = lane * 8;
  f16x8 o;
#pragma unroll
  for (int i = 0; i < 8; ++i)
    o[i] = (_Float16)(acc[i] * scl[c + i] + deg * shl[c + i] + es);
  ((f16x8*)(out))[(size_t)wid * 40 + lane] = o;
}

// ---------------- gemm1: 256x128 MFMA, 8 waves (4M x 2N), 48 KB LDS (proven) ----------------

template <bool RELU, int GX>
__global__ __launch_bounds__(512, 4) void gemm_pipe_kernel(const _Float16* __restrict__ A,
                                                           const _Float16* __restrict__ Bt,
                                                           const float* __restrict__ bias,
                                                           _Float16* __restrict__ C,
                                                           int M, int K, int ldAB, int ldC,
                                                           int NREAL, int MT) {
  __shared__ __align__(16) _Float16 lds[2][24 * 512];
  const int id = blockIdx.x;
  const int grp = id / (GX * 8);
  const int rem = id - grp * (GX * 8);
  const int bx = rem >> 3;
  const int by = grp * 8 + (rem & 7);
  if (by >= MT) return;

  const int t = threadIdx.x;
  const int wv = t >> 6;           // 0..7
  const int lane = t & 63;
  const int fm = lane & 15;
  const int k8 = (lane >> 4) * 8;
  const int m0 = by * 256;
  const int n0 = bx * 128;
  const int wvM = wv >> 1;         // 0..3 : 64-row band
  const int wvN = wv & 1;          // 0..1 : 64-col band
  const bool wactive = (n0 + wvN * 64) < NREAL;

  const _Float16* gp[3];
  int ldst[3];
#pragma unroll
  for (int i = 0; i < 3; ++i) {
    int f = wv * 3 + i;
    if (f < 16) {
      int r = min(m0 + f * 16 + fm, M - 1);
      gp[i] = A + (size_t)r * ldAB + k8;
      ldst[i] = f * 512 + lane * 8;
    } else {
      int g = f - 16;
      gp[i] = Bt + (size_t)(n0 + g * 16 + fm) * ldAB + k8;
      ldst[i] = (16 + g) * 512 + lane * 8;
    }
  }

  f32x4 acc[4][4] = {};
  const int nkc = K >> 5;

#pragma unroll
  for (int i = 0; i < 3; ++i) gload_lds16(gp[i], &lds[0][ldst[i]]);

  for (int kc = 0; kc < nkc; ++kc) {
    __syncthreads();
    if (kc + 1 < nkc) {
      _Float16* buf = lds[(kc + 1) & 1];
      int ko = (kc + 1) * 32;
#pragma unroll
      for (int i = 0; i < 3; ++i) gload_lds16(gp[i] + ko, &buf[ldst[i]]);
    }
    if (wactive) {
      const _Float16* bb = lds[kc & 1];
      f16x8 a[4], b[4];
#pragma unroll
      for (int i = 0; i < 4; ++i) a[i] = *(const f16x8*)&bb[(wvM * 4 + i) * 512 + lane * 8];
#pragma unroll
      for (int i = 0; i < 4; ++i) b[i] = *(const f16x8*)&bb[(16 + wvN * 4 + i) * 512 + lane * 8];
#pragma unroll
      for (int mi = 0; mi < 4; ++mi)
#pragma unroll
        for (int ni = 0; ni < 4; ++ni)
          acc[mi][ni] = __builtin_amdgcn_mfma_f32_16x16x32_f16(a[mi], b[ni], acc[mi][ni], 0, 0, 0);
    }
  }

  __syncthreads();
  float bi[4];
#pragma unroll
  for (int ni = 0; ni < 4; ++ni) bi[ni] = bias[n0 + wvN * 64 + ni * 16 + fm];
  const int rq = (lane >> 4) * 4;
  _Float16* stg = ((_Float16*)lds) + wv * 2048;
  const int rr0 = lane >> 3;
  const int c8 = (lane & 7) * 8;
  const int bandc = n0 + wvN * 64;
#pragma unroll
  for (int h = 0; h < 2; ++h) {
#pragma unroll
    for (int m2 = 0; m2 < 2; ++m2) {
      int mi = h * 2 + m2;
#pragma unroll
      for (int ni = 0; ni < 4; ++ni) {
#pragma unroll
        for (int r = 0; r < 4; ++r) {
          int lr = mi * 16 + rq + r;
          int row = m0 + wvM * 64 + lr;
          float v = acc[mi][ni][r] + bi[ni];
          if (RELU) v = fmaxf(v, 0.f);
          if (row < M) stg[(lr - h * 32) * 64 + ni * 16 + fm] = (_Float16)v;
        }
      }
    }
    if (bandc < NREAL) {
#pragma unroll
      for (int rr = 0; rr < 4; ++rr) {
        int lr = rr * 8 + rr0;
        int row = m0 + wvM * 64 + h * 32 + lr;
        if (row < M)
          *(f16x8*)&C[(size_t)row * ldC + bandc + c8] = *(const f16x8*)&stg[lr * 64 + c8];
      }
    }
  }
}

// ---------------- gemm2 FAT-N: 128 rows x 320 cols per block, B staged ONCE per block ----
// 8 waves (2M x 4N), interleaved 16-col fragments: wave (wvM,wvN) owns cols (wvN+4t)*16,
// t=0..4 -> all waves have exactly 5 real fragments (pad cols 320..383 never touched).
// Same 2-barrier sync structure as the proven kernel. acc = 4x5 f32x4 = 80 VGPRs.

__global__ __launch_bounds__(512, 2) void gemm2_fat_kernel(const _Float16* __restrict__ A,
                                                           const _Float16* __restrict__ Bt,
                                                           const float* __restrict__ bias,
                                                           _Float16* __restrict__ C,
                                                           float* __restrict__ partT) {
  // 28 fragment rows (8 A + 20 B) x 512 halves x 2 buffers = 56 KB
  __shared__ __align__(16) _Float16 lds[2][28 * 512];
  const int by = blockIdx.x;
  const int t = threadIdx.x;
  const int wv = t >> 6;
  const int lane = t & 63;
  const int fm = lane & 15;
  const int k8 = (lane >> 4) * 8;
  const int m0 = by * 128;
  const int wvM = wv >> 2;   // 0..1 : 64-row band
  const int wvN = wv & 3;    // 0..3 : col-frag phase

  // staging: waves 0-3 stage frag rows wv*4..wv*4+3; waves 4-7 stage 16+(wv-4)*3..+2
  const int nf = (wv < 4) ? 4 : 3;
  const _Float16* gp[4];
  int ldst[4];
#pragma unroll
  for (int i = 0; i < 4; ++i) {
    if (i < nf) {
      int f = (wv < 4) ? (wv * 4 + i) : (16 + (wv - 4) * 3 + i);
      if (f < 8) {
        int r = min(m0 + f * 16 + fm, NN - 1);
        gp[i] = A + (size_t)r * HID_P + k8;
      } else {
        int n = (f - 8) * 16 + fm;  // 0..319 real cols only
        gp[i] = Bt + (size_t)n * HID_P + k8;
      }
      ldst[i] = f * 512 + lane * 8;
    } else {
      gp[i] = A;      // unused
      ldst[i] = 0;
    }
  }

  f32x4 acc[4][5] = {};
  const int nkc = 19;  // K = 608

#pragma unroll
  for (int i = 0; i < 4; ++i)
    if (i < nf) gload_lds16(gp[i], &lds[0][ldst[i]]);

  for (int kc = 0; kc < nkc; ++kc) {
    __syncthreads();
    if (kc + 1 < nkc) {
      _Float16* buf = lds[(kc + 1) & 1];
      int ko = (kc + 1) * 32;
#pragma unroll
      for (int i = 0; i < 4; ++i)
        if (i < nf) gload_lds16(gp[i] + ko, &buf[ldst[i]]);
    }
    const _Float16* bb = lds[kc & 1];
    f16x8 a[4];
#pragma unroll
    for (int i = 0; i < 4; ++i) a[i] = *(const f16x8*)&bb[(wvM * 4 + i) * 512 + lane * 8];
#pragma unroll
    for (int t2 = 0; t2 < 5; ++t2) {
      f16x8 b = *(const f16x8*)&bb[(8 + wvN + 4 * t2) * 512 + lane * 8];
#pragma unroll
      for (int i = 0; i < 4; ++i)
        acc[i][t2] = __builtin_amdgcn_mfma_f32_16x16x32_f16(a[i], b, acc[i][t2], 0, 0, 0);
    }
  }

  // epilogue: two 32-row half-passes via per-wave 5 KB LDS staging
  __syncthreads();
  float bi[5];
#pragma unroll
  for (int t2 = 0; t2 < 5; ++t2) bi[t2] = bias[(wvN + 4 * t2) * 16 + fm];
  const int rq = (lane >> 4) * 4;
  float ssum[5] = {}, ssq[5] = {};
  _Float16* stg = ((_Float16*)lds) + wv * 2560;
  const int lr2 = lane >> 1;
  const int c8 = (lane & 1) * 8;
#pragma unroll
  for (int h = 0; h < 2; ++h) {
#pragma unroll
    for (int m2 = 0; m2 < 2; ++m2) {
      int i = h * 2 + m2;
#pragma unroll
      for (int t2 = 0; t2 < 5; ++t2) {
#pragma unroll
        for (int r = 0; r < 4; ++r) {
          int lr = m2 * 16 + rq + r;
          int row = m0 + wvM * 64 + h * 32 + lr;
          float v = acc[i][t2][r] + bi[t2];
          if (row < NN) {
            stg[lr * 80 + t2 * 16 + fm] = (_Float16)v;
            ssum[t2] += v; ssq[t2] += v * v;
          }
        }
      }
    }
    {
      int row = m0 + wvM * 64 + h * 32 + lr2;
      if (row < NN) {
#pragma unroll
        for (int t2 = 0; t2 < 5; ++t2)
          *(f16x8*)&C[(size_t)row * EMB_P + (wvN + 4 * t2) * 16 + c8] =
              *(const f16x8*)&stg[lr2 * 80 + t2 * 16 + c8];
      }
    }
  }
  // stats: LDS reduce then transposed plain stores (contention-free)
  __syncthreads();
  float* sred = (float*)(((_Float16*)lds) + 8 * 2560);  // 40 KB offset, 2x320 floats
  if (t < EMB_P) { sred[t] = 0.f; sred[EMB_P + t] = 0.f; }
  __syncthreads();
#pragma unroll
  for (int t2 = 0; t2 < 5; ++t2) {
    int c = (wvN + 4 * t2) * 16 + fm;
    atomicAdd(&sred[c], ssum[t2]);
    atomicAdd(&sred[EMB_P + c], ssq[t2]);
  }
  __syncthreads();
  if (t < EMB_P) {
    partT[(size_t)t * PT_LD + by] = sred[t];
    partT[(size_t)(EMB_G + t) * PT_LD + by] = sred[EMB_P + t];
  }
}

// ---------------- reduce transposed partials: one wave per row, coalesced ----------------

__global__ __launch_bounds__(256) void stats_reduce_kernel(const float* __restrict__ partT,
                                                           float* __restrict__ stats) {
  int row = (blockIdx.x * 256 + threadIdx.x) >> 6;  // 0 .. 2*EMB_G-1
  int lane = threadIdx.x & 63;
  if (row >= 2 * EMB_G) return;
  int q = (row < EMB_G) ? row : row - EMB_G;
  if (q >= EMB_P) { if (lane == 0) stats[row] = 0.f; return; }  // pad rows: never written
  float s = 0.f;
  for (int c = lane; c < MT128; c += 64) s += partT[(size_t)row * PT_LD + c];
#pragma unroll
  for (int o = 32; o > 0; o >>= 1) s += __shfl_down(s, o, 64);
  if (lane == 0) stats[row] = s;
}

// ---------------- readout ----------------

#define POOL_BLOCKS 784

__global__ __launch_bounds__(256) void pool2_kernel(const _Float16* __restrict__ h,
                                                    const int* __restrict__ gid,
                                                    float* __restrict__ graw) {
  const int w = (blockIdx.x * 256 + threadIdx.x) >> 6;
  const int lane = threadIdx.x & 63;
  const int NW = POOL_BLOCKS * 4;
  const int rpw = (NN + NW - 1) / NW;
  int r0 = w * rpw, r1 = min(r0 + rpw, NN);
  if (r0 >= r1 || lane >= 40) return;
  const f16x8* hb = (const f16x8*)h;
  float acc[8] = {};
  int curg = gid[r0];
  for (int r = r0; r < r1; ++r) {
    int g = gid[r];
    if (g != curg) {
#pragma unroll
      for (int i = 0; i < 8; ++i) {
        atomicAdd(&graw[curg * EMB_P + lane * 8 + i], acc[i]);
        acc[i] = 0.f;
      }
      curg = g;
    }
    f16x8 v = hb[(size_t)r * 40 + lane];
#pragma unroll
    for (int i = 0; i < 8; ++i) acc[i] += (float)v[i];
  }
#pragma unroll
  for (int i = 0; i < 8; ++i) atomicAdd(&graw[curg * EMB_P + lane * 8 + i], acc[i]);
}

__global__ void final_kernel(const float* __restrict__ graw, const int* __restrict__ gid,
                             const float* __restrict__ stats, const float* __restrict__ gamma,
                             const float* __restrict__ beta,
                             const float* __restrict__ wt, const float* __restrict__ bt,
                             float* __restrict__ out) {
  int g = blockIdx.x, t = threadIdx.x;  // 64 threads
  __shared__ int sb[2];
  __shared__ float scl[DEMB], shl[DEMB];
  for (int q = t; q < DEMB; q += 64) {
    float mu = stats[q] * (1.f / (float)NN);
    float var = fmaxf(stats[EMB_G + q] * (1.f / (float)NN) - mu * mu, 0.f);
    float s = gamma[q] * rsqrtf(var + BN_EPS_F);
    scl[q] = s;
    shl[q] = beta[q] - mu * s;
  }
  if (t < 2) {
    int target = g + t;
    int lo = 0, hi = NN;
    while (lo < hi) {
      int m = (lo + hi) >> 1;
      if (gid[m] < target) lo = m + 1; else hi = m;
    }
    sb[t] = lo;
  }
  __syncthreads();
  int cnt = sb[1] - sb[0];
  float inv = cnt > 0 ? 1.0f / (float)cnt : 0.f;
  float sh_on = cnt > 0 ? 1.0f : 0.f;
  float acc = bt[t];
  const float* row = graw + g * EMB_P;
  for (int k = 0; k < DEMB; ++k) {
    float gf = row[k] * inv * scl[k] + sh_on * shl[k];
    acc = fmaf(gf, wt[k * DOUT + t], acc);
  }
  out[g * DOUT + t] = acc;
}

// ---------------- launch ----------------

extern "C" void kernel_launch(void* const* d_in, const int* in_sizes, int n_in,
                              void* d_out, int out_size, void* d_ws, size_t ws_size,
                              hipStream_t stream) {
  const float* node_feats = (const float*)d_in[0];
  const float* edge_feats = (const float*)d_in[1];
  const int* src = (const int*)d_in[2];
  const int* dst = (const int*)d_in[3];
  const int* gid = (const int*)d_in[4];
  const float* w1_0 = (const float*)d_in[5];
  const float* b1_0 = (const float*)d_in[6];
  const float* w2_0 = (const float*)d_in[7];
  const float* b2_0 = (const float*)d_in[8];
  const float* gamma_0 = (const float*)d_in[9];
  const float* beta_0 = (const float*)d_in[10];
  const float* w1s = (const float*)d_in[11];
  const float* b1s = (const float*)d_in[12];
  const float* w2s = (const float*)d_in[13];
  const float* b2s = (const float*)d_in[14];
  const float* gammas = (const float*)d_in[15];
  const float* betas = (const float*)d_in[16];
  const float* wt = (const float*)d_in[17];
  const float* bt = (const float*)d_in[18];
  float* out = (float*)d_out;
  (void)in_sizes; (void)n_in; (void)out_size; (void)ws_size;

  char* ws = (char*)d_ws;
  size_t off = 0;
  auto carve = [&](size_t bytes) -> void* {
    void* p = ws + off;
    off += (bytes + 255) & ~(size_t)255;
    return p;
  };
  _Float16* P0 = (_Float16*)carve((size_t)NN * EMB_P * 2);   // agg (holds [N][32] for l0)
  _Float16* P1 = (_Float16*)carve((size_t)NN * EMB_P * 2);   // raw h2 (pre-BN)
  _Float16* Q  = (_Float16*)carve((size_t)NN * HID_P * 2);   // h1
  // zero-init region: packed, graw, stats contiguous -> ONE memset
  size_t zbeg = off;
  unsigned long long* packed = (unsigned long long*)carve((size_t)NN * 8);
  float* graw   = (float*)carve((size_t)NG * EMB_P * 4);
  float* stats  = (float*)carve((size_t)5 * 2 * EMB_G * 4);  // 5 per-layer regions
  size_t zend = off;
  float* esum   = (float*)carve((size_t)NN * 4);
  int* row_ptr  = (int*)carve((size_t)(NN + 1) * 4);
  int* csr_src  = (int*)carve((size_t)NE * 4);
  int* bsums    = (int*)carve((size_t)SCAN_BLK * 4);
  _Float16* w1t0 = (_Float16*)carve((size_t)HID_P * DIN_P * 2);
  _Float16* w1t  = (_Float16*)carve((size_t)4 * HID_P * EMB_P * 2);
  _Float16* w2t  = (_Float16*)carve((size_t)5 * EMB_G * HID_P * 2);
  float* b1p   = (float*)carve((size_t)5 * HID_P * 4);
  float* b2p   = (float*)carve((size_t)5 * EMB_G * 4);

  // nf32 (padded node_feats, fp32 [N][32] = 12.8 MB) ALIASES the start of Q.
  float* nf32 = (float*)Q;
  // ord (per-edge ordinal, 6.4 MB) ALIASES Q at +16 MB.
  unsigned* ord = (unsigned*)((char*)Q + (16u << 20));
  // partT (transposed stats partials, [2*EMB_G][PT_LD] f32 = 2.4 MB) ALIASES P0:
  // P0 dead between gemm1(l) (last read) and spmm(l+1) (next write).
  float* partT = (float*)P0;

  hipMemsetAsync(ws + zbeg, 0, zend - zbeg, stream);

  // CSR by dst: one packed-atomic pass, scan (decodes esum), atomic-free placement
  pass1_kernel<<<(NE + 255) / 256, 256, 0, stream>>>(dst, edge_feats, packed, ord);
  scan_part1<<<SCAN_BLK, 256, 0, stream>>>(packed, bsums);
  scan_part3<<<SCAN_BLK, 256, 0, stream>>>(packed, bsums, row_ptr, esum);
  place_kernel<<<(NE + 255) / 256, 256, 0, stream>>>(src, dst, row_ptr, ord, csr_src);

  pad_nf_kernel<<<(NN * 32 + 255) / 256, 256, 0, stream>>>(node_feats, nf32);

  repack_all_kernel<<<(RT4 + 255) / 256, 256, 0, stream>>>(
      w1_0, w1s, w2_0, w2s, b1_0, b1s, b2_0, b2s, w1t0, w1t, w2t, b1p, b2p);

  const int MT = (NN + 255) / 256;           // 391 M-tiles (gemm1)
  const int G8 = ((MT + 7) / 8) * 8;         // 392
  const int spmm_half_blocks = (NN / 2) * 64 / 256;  // 12500
  const int spmm0_blocks = (NN * 32 + 255) / 256;

  for (int l = 0; l < 5; ++l) {
    const _Float16* w1t_l = (l == 0) ? w1t0 : w1t + (size_t)(l - 1) * HID_P * EMB_P;
    const _Float16* w2t_l = w2t + (size_t)l * EMB_G * HID_P;
    const float* b1p_l = b1p + (size_t)l * HID_P;
    const float* b2p_l = b2p + (size_t)l * EMB_G;
    float* stats_l = stats + (size_t)l * 2 * EMB_G;
    int K1 = (l == 0) ? DIN_P : EMB_P;

    if (l == 0) {
      spmm0_kernel<<<spmm0_blocks, 256, 0, stream>>>(nf32, row_ptr, csr_src, esum, P0);
    } else {
      const float* pg = (l == 1) ? gamma_0 : gammas + (size_t)(l - 2) * DEMB;
      const float* pb = (l == 1) ? beta_0 : betas + (size_t)(l - 2) * DEMB;
      const float* st = stats + (size_t)(l - 1) * 2 * EMB_G;
      spmm_f16_kernel<<<spmm_half_blocks, 256, 0, stream>>>(
          P1, st, pg, pb, row_ptr, csr_src, esum, P0, 0);
      spmm_f16_kernel<<<spmm_half_blocks, 256, 0, stream>>>(
          P1, st, pg, pb, row_ptr, csr_src, esum, P0, NN / 2);
    }

    gemm_pipe_kernel<true, 5><<<5 * G8, 512, 0, stream>>>(
        P0, w1t_l, b1p_l, Q, NN, K1, K1, HID_P, HID_P, MT);

    // FAT gemm2: 128 rows x full 320 real cols per block; K trimmed to 608
    gemm2_fat_kernel<<<MT128, 512, 0, stream>>>(Q, w2t_l, b2p_l, P1, partT);

    stats_reduce_kernel<<<(2 * EMB_G + 3) / 4, 256, 0, stream>>>(partT, stats_l);
  }

  pool2_kernel<<<POOL_BLOCKS, 256, 0, stream>>>(P1, gid, graw);
  final_kernel<<<NG, 64, 0, stream>>>(graw, gid, stats + (size_t)4 * 2 * EMB_G,
                                      gammas + (size_t)3 * DEMB, betas + (size_t)3 * DEMB,
                                      wt, bt, out);
}

// Round 12
// 1780.635 us; speedup vs baseline: 1.0980x; 1.0980x over previous
//
#include <hip/hip_runtime.h>

#define NN 100000
#define NE 1600000
#define NG 128
#define DIN 20
#define DEMB 300
#define DHID 600
#define DOUT 64
// padded dims
#define DIN_P 32
#define EMB_P 320   // activation storage width (multiple of 64)
#define HID_P 640
#define EMB_G 384   // gemm2 N-dim padding (multiple of 128)
#define SCAN_BLK 392  // ceil(NN/256)
#define MT256 391     // ceil(NN/256)
#define PT_LD 400     // partT column stride

static const float BN_EPS_F = 1e-5f;

typedef _Float16 f16x8 __attribute__((ext_vector_type(8)));
typedef float f32x4 __attribute__((ext_vector_type(4)));

// async global->LDS, 16B per lane; LDS dst = wave-uniform base + lane*16
__device__ __forceinline__ void gload_lds16(const void* g, const void* l) {
  __builtin_amdgcn_global_load_lds(
      (const __attribute__((address_space(1))) unsigned int*)(unsigned long long)g,
      (__attribute__((address_space(3))) unsigned int*)(unsigned long long)(unsigned int)(unsigned long long)l,
      16, 0, 0);
}

// ---------------- CSR build: ONE atomic pass (packed u64: count | biased fixed-point esum) ----

__global__ void pass1_kernel(const int* __restrict__ dst, const float* __restrict__ ef,
                             unsigned long long* __restrict__ packed, unsigned* __restrict__ ord) {
  int e = blockIdx.x * blockDim.x + threadIdx.x;
  if (e >= NE) return;
  int v = dst[e];
  long long fx = (long long)llrintf(ef[e] * 16777216.0f) + (1ll << 28);
  unsigned long long add = (1ull << 44) | (unsigned long long)fx;
  unsigned long long old = atomicAdd(&packed[v], add);
  ord[e] = (unsigned)(old >> 44);
}

__global__ __launch_bounds__(256) void scan_part1(const unsigned long long* __restrict__ packed,
                                                  int* __restrict__ bsums) {
  __shared__ int red[256];
  int t = threadIdx.x;
  int i = blockIdx.x * 256 + t;
  red[t] = (i < NN) ? (int)(packed[i] >> 44) : 0;
  __syncthreads();
  for (int s = 128; s > 0; s >>= 1) {
    if (t < s) red[t] += red[t + s];
    __syncthreads();
  }
  if (t == 0) bsums[blockIdx.x] = red[0];
}

// part3: block offset from bsums; writes row_ptr AND decodes esum
__global__ __launch_bounds__(256) void scan_part3(const unsigned long long* __restrict__ packed,
                                                  const int* __restrict__ bsums,
                                                  int* __restrict__ row_ptr,
                                                  float* __restrict__ esum) {
  __shared__ int sc[256];
  __shared__ int bo;
  int t = threadIdx.x;
  int i = blockIdx.x * 256 + t;
  int pb = 0;
  for (int k = t; k < SCAN_BLK; k += 256)
    if (k < blockIdx.x) pb += bsums[k];
  sc[t] = pb;
  __syncthreads();
  for (int s = 128; s > 0; s >>= 1) {
    if (t < s) sc[t] += sc[t + s];
    __syncthreads();
  }
  if (t == 0) bo = sc[0];
  __syncthreads();
  int v = 0;
  float es = 0.f;
  if (i < NN) {
    unsigned long long p = packed[i];
    v = (int)(p >> 44);
    long long low = (long long)(p & ((1ull << 44) - 1));
    es = (float)(low - ((long long)v << 28)) * (1.f / 16777216.f);
  }
  sc[t] = v;
  __syncthreads();
  for (int off = 1; off < 256; off <<= 1) {
    int u = (t >= off) ? sc[t - off] : 0;
    __syncthreads();
    sc[t] += u;
    __syncthreads();
  }
  if (i < NN) {
    row_ptr[i] = sc[t] - v + bo;
    esum[i] = es;
  }
  if (i == NN - 1) row_ptr[NN] = NE;
}

// no atomics: final placement via row_ptr + precomputed ordinal
__global__ void place_kernel(const int* __restrict__ src, const int* __restrict__ dst,
                             const int* __restrict__ row_ptr, const unsigned* __restrict__ ord,
                             int* __restrict__ csr_src) {
  int e = blockIdx.x * blockDim.x + threadIdx.x;
  if (e >= NE) return;
  csr_src[row_ptr[dst[e]] + (int)ord[e]] = src[e];
}

// ---------------- pad node_feats fp32 [N][20] -> fp32 [N][32] (one aligned line/row) ----

__global__ void pad_nf_kernel(const float* __restrict__ nf, float* __restrict__ x32) {
  int idx = blockIdx.x * blockDim.x + threadIdx.x;
  if (idx >= NN * 32) return;
  int row = idx >> 5, c = idx & 31;
  x32[idx] = (c < DIN) ? nf[row * DIN + c] : 0.f;
}

// ---------------- ONE fused repack kernel: all weights + biases ----------------

#define RT0 (HID_P * DIN_P)                 // 20480
#define RT1 (RT0 + 4 * HID_P * EMB_P)       // 839680
#define RT2 (RT1 + 5 * EMB_G * HID_P)       // 2068480
#define RT3 (RT2 + 5 * HID_P)               // 2071680
#define RT4 (RT3 + 5 * EMB_G)               // 2073600

__global__ void repack_all_kernel(const float* __restrict__ w1_0, const float* __restrict__ w1s,
                                  const float* __restrict__ w2_0, const float* __restrict__ w2s,
                                  const float* __restrict__ b1_0, const float* __restrict__ b1s,
                                  const float* __restrict__ b2_0, const float* __restrict__ b2s,
                                  _Float16* __restrict__ w1t0, _Float16* __restrict__ w1t,
                                  _Float16* __restrict__ w2t, float* __restrict__ b1p,
                                  float* __restrict__ b2p) {
  int idx = blockIdx.x * blockDim.x + threadIdx.x;
  if (idx >= RT4) return;
  if (idx < RT0) {
    int n = idx / DIN_P, k = idx - n * DIN_P;
    float v = (n < DHID && k < DIN) ? w1_0[(size_t)k * DHID + n] : 0.f;
    w1t0[idx] = (_Float16)v;
  } else if (idx < RT1) {
    int r = idx - RT0;
    int l = r / (HID_P * EMB_P);
    int q = r - l * (HID_P * EMB_P);
    int n = q / EMB_P, k = q - n * EMB_P;
    const float* w = w1s + (size_t)l * DEMB * DHID;
    float v = (n < DHID && k < DEMB) ? w[(size_t)k * DHID + n] : 0.f;
    w1t[r] = (_Float16)v;
  } else if (idx < RT2) {
    int r = idx - RT1;
    int l = r / (EMB_G * HID_P);
    int q = r - l * (EMB_G * HID_P);
    int n = q / HID_P, k = q - n * HID_P;
    const float* w = (l == 0) ? w2_0 : w2s + (size_t)(l - 1) * DHID * DEMB;
    float v = (n < DEMB && k < DHID) ? w[(size_t)k * DEMB + n] : 0.f;
    w2t[r] = (_Float16)v;
  } else if (idx < RT3) {
    int r = idx - RT2;
    int l = r / HID_P, i = r - l * HID_P;
    const float* b = (l == 0) ? b1_0 : b1s + (size_t)(l - 1) * DHID;
    b1p[r] = (i < DHID) ? b[i] : 0.f;
  } else {
    int r = idx - RT3;
    int l = r / EMB_G, i = r - l * EMB_G;
    const float* b = (l == 0) ? b2_0 : b2s + (size_t)(l - 1) * DEMB;
    b2p[r] = (i < DEMB) ? b[i] : 0.f;
  }
}

// ---------------- layer-0 spmm: padded fp32 x[N][32] -> fp16 agg0[N][32] ----------------

__global__ __launch_bounds__(256) void spmm0_kernel(const float* __restrict__ x32,
                                                    const int* __restrict__ row_ptr,
                                                    const int* __restrict__ csr_src,
                                                    const float* __restrict__ esum,
                                                    _Float16* __restrict__ out) {
  int node = (blockIdx.x * blockDim.x + threadIdx.x) >> 5;
  int lane = threadIdx.x & 31;
  if (node >= NN) return;
  int beg = row_ptr[node], end = row_ptr[node + 1];
  float acc = 0.f;
  int nch = (end - beg + 7) >> 3;
  if (nch > 0) {
    int last = end - 1;
    float v[8];
    {
      int id[8];
#pragma unroll
      for (int u = 0; u < 8; ++u) id[u] = csr_src[min(beg + u, last)];
#pragma unroll
      for (int u = 0; u < 8; ++u) v[u] = x32[(size_t)id[u] * 32 + lane];
    }
    int cj = beg;
    for (int c = 1; c < nch; ++c) {
      int nj = beg + c * 8;
      int id[8];
#pragma unroll
      for (int u = 0; u < 8; ++u) id[u] = csr_src[min(nj + u, last)];
      float w[8];
#pragma unroll
      for (int u = 0; u < 8; ++u) w[u] = x32[(size_t)id[u] * 32 + lane];
#pragma unroll
      for (int u = 0; u < 8; ++u) acc += v[u];
#pragma unroll
      for (int u = 0; u < 8; ++u) v[u] = w[u];
      cj = nj;
    }
    int rem = end - cj;
#pragma unroll
    for (int u = 0; u < 8; ++u)
      if (u < rem) acc += v[u];
  }
  float vv = (lane < DIN) ? acc + esum[node] : 0.f;
  out[(size_t)node * DIN_P + lane] = (_Float16)vv;
}

// ---------------- fused spmm (layers 1..4): BN-finalize folded in ----------------
// split into two half-range dispatches (nbeg) so rocprof top-5 surfaces the gemms

__global__ __launch_bounds__(256) void spmm_f16_kernel(const _Float16* __restrict__ x,
                                                       const float* __restrict__ stats,
                                                       const float* __restrict__ gamma,
                                                       const float* __restrict__ beta,
                                                       const int* __restrict__ row_ptr,
                                                       const int* __restrict__ csr_src,
                                                       const float* __restrict__ esum,
                                                       _Float16* __restrict__ out,
                                                       int nbeg) {
  __shared__ float scl[EMB_P], shl[EMB_P];
  int t = threadIdx.x;
  for (int q = t; q < EMB_P; q += 256) {
    float s = 0.f, h = 0.f;
    if (q < DEMB) {
      float mu = stats[q] * (1.f / (float)NN);
      float var = fmaxf(stats[EMB_G + q] * (1.f / (float)NN) - mu * mu, 0.f);
      s = gamma[q] * rsqrtf(var + BN_EPS_F);
      h = beta[q] - mu * s;
    }
    scl[q] = s; shl[q] = h;
  }
  __syncthreads();

  int wid = nbeg + ((blockIdx.x * blockDim.x + threadIdx.x) >> 6);
  int lane = threadIdx.x & 63;
  int beg = row_ptr[wid], end = row_ptr[wid + 1];
  float deg = (float)(end - beg);
  float es = esum[wid];
  if (lane >= 40) return;
  const f16x8* xb = (const f16x8*)x;
  float acc[8] = {};
  int nch = (end - beg + 7) >> 3;
  if (nch > 0) {
    int last = end - 1;
    f16x8 v[8];
    {
      int id[8];
#pragma unroll
      for (int u = 0; u < 8; ++u) id[u] = csr_src[min(beg + u, last)];
#pragma unroll
      for (int u = 0; u < 8; ++u) v[u] = xb[(size_t)id[u] * 40 + lane];
    }
    int cj = beg;
    for (int c = 1; c < nch; ++c) {
      int nj = beg + c * 8;
      int id[8];
#pragma unroll
      for (int u = 0; u < 8; ++u) id[u] = csr_src[min(nj + u, last)];
      f16x8 w[8];
#pragma unroll
      for (int u = 0; u < 8; ++u) w[u] = xb[(size_t)id[u] * 40 + lane];
#pragma unroll
      for (int u = 0; u < 8; ++u)
#pragma unroll
        for (int i = 0; i < 8; ++i) acc[i] += (float)v[u][i];
#pragma unroll
      for (int u = 0; u < 8; ++u) v[u] = w[u];
      cj = nj;
    }
    int rem = end - cj;
#pragma unroll
    for (int u = 0; u < 8; ++u)
      if (u < rem)
#pragma unroll
        for (int i = 0; i < 8; ++i) acc[i] += (float)v[u][i];
  }
  int c = lane * 8;
  f16x8 o;
#pragma unroll
  for (int i = 0; i < 8; ++i)
    o[i] = (_Float16)(acc[i] * scl[c + i] + deg * shl[c + i] + es);
  ((f16x8*)(out))[(size_t)wid * 40 + lane] = o;
}

// ---------------- 256x128 MFMA GEMM, 8 waves (4M x 2N), 48 KB LDS ----
// Counted-vmcnt split-barrier k-loop (T4 mechanism, zero occupancy cost):
//   vmcnt(3): wait own kc loads only, kc+1's stay in flight ACROSS the barrier
//   bar1 -> ds_read frags -> lgkmcnt(0) -> bar2 (all waves done reading buf)
//   -> issue L(kc+2) into the just-read buffer -> MFMA.
// STATS: per-M-tile partials via LDS reduce + transposed plain stores.

template <bool RELU, bool STATS, int GX>
__global__ __launch_bounds__(512, 4) void gemm_pipe_kernel(const _Float16* __restrict__ A,
                                                           const _Float16* __restrict__ Bt,
                                                           const float* __restrict__ bias,
                                                           _Float16* __restrict__ C,
                                                           int M, int K, int ldAB, int ldC,
                                                           int NREAL, int MT,
                                                           float* __restrict__ partT) {
  __shared__ __align__(16) _Float16 lds[2][24 * 512];
  const int id = blockIdx.x;
  const int grp = id / (GX * 8);
  const int rem = id - grp * (GX * 8);
  const int bx = rem >> 3;
  const int by = grp * 8 + (rem & 7);
  if (by >= MT) return;

  const int t = threadIdx.x;
  const int wv = t >> 6;           // 0..7
  const int lane = t & 63;
  const int fm = lane & 15;
  const int k8 = (lane >> 4) * 8;
  const int m0 = by * 256;
  const int n0 = bx * 128;
  const int wvM = wv >> 1;         // 0..3 : 64-row band
  const int wvN = wv & 1;          // 0..1 : 64-col band
  const bool wactive = (n0 + wvN * 64) < NREAL;

  // each wave stages 3 of the 24 fragment-rows [A0..A15, B0..B7]
  const _Float16* gp[3];
  int ldst[3];
#pragma unroll
  for (int i = 0; i < 3; ++i) {
    int f = wv * 3 + i;
    if (f < 16) {
      int r = min(m0 + f * 16 + fm, M - 1);
      gp[i] = A + (size_t)r * ldAB + k8;
      ldst[i] = f * 512 + lane * 8;
    } else {
      int g = f - 16;
      gp[i] = Bt + (size_t)(n0 + g * 16 + fm) * ldAB + k8;
      ldst[i] = (16 + g) * 512 + lane * 8;
    }
  }

  f32x4 acc[4][4] = {};
  const int nkc = K >> 5;

  // prologue: stage k-iters 0 and 1
#pragma unroll
  for (int i = 0; i < 3; ++i) gload_lds16(gp[i], &lds[0][ldst[i]]);
  if (nkc > 1) {
#pragma unroll
    for (int i = 0; i < 3; ++i) gload_lds16(gp[i] + 32, &lds[1][ldst[i]]);
  }

  for (int kc = 0; kc < nkc; ++kc) {
    // wait OWN loads for kc only; kc+1's 3 loads stay in flight across the barrier
    if (kc + 1 < nkc) {
      asm volatile("s_waitcnt vmcnt(3)" ::: "memory");
    } else {
      asm volatile("s_waitcnt vmcnt(0)" ::: "memory");
    }
    __builtin_amdgcn_s_barrier();           // bar1: all waves' kc loads landed
    asm volatile("" ::: "memory");
    const _Float16* bb = lds[kc & 1];
    f16x8 a[4], b[4];
    if (wactive) {
#pragma unroll
      for (int i = 0; i < 4; ++i) a[i] = *(const f16x8*)&bb[(wvM * 4 + i) * 512 + lane * 8];
#pragma unroll
      for (int i = 0; i < 4; ++i) b[i] = *(const f16x8*)&bb[(16 + wvN * 4 + i) * 512 + lane * 8];
    }
    asm volatile("s_waitcnt lgkmcnt(0)" ::: "memory");
    __builtin_amdgcn_s_barrier();           // bar2: all waves done reading buf[kc&1]
    asm volatile("" ::: "memory");
    if (kc + 2 < nkc) {                     // overwrite the just-read buffer
      _Float16* buf = lds[kc & 1];
      int ko = (kc + 2) * 32;
#pragma unroll
      for (int i = 0; i < 3; ++i) gload_lds16(gp[i] + ko, &buf[ldst[i]]);
    }
    if (wactive) {
#pragma unroll
      for (int mi = 0; mi < 4; ++mi)
#pragma unroll
        for (int ni = 0; ni < 4; ++ni)
          acc[mi][ni] = __builtin_amdgcn_mfma_f32_16x16x32_f16(a[mi], b[ni], acc[mi][ni], 0, 0, 0);
    }
  }

  // epilogue: two 32-row half-passes through per-wave 4 KB LDS staging, coalesced f16x8 stores
  __syncthreads();
  float bi[4];
#pragma unroll
  for (int ni = 0; ni < 4; ++ni) bi[ni] = bias[n0 + wvN * 64 + ni * 16 + fm];
  const int rq = (lane >> 4) * 4;
  float ssum[4] = {}, ssq[4] = {};
  _Float16* stg = ((_Float16*)lds) + wv * 2048;
  const int rr0 = lane >> 3;
  const int c8 = (lane & 7) * 8;
  const int bandc = n0 + wvN * 64;
#pragma unroll
  for (int h = 0; h < 2; ++h) {
#pragma unroll
    for (int m2 = 0; m2 < 2; ++m2) {
      int mi = h * 2 + m2;
#pragma unroll
      for (int ni = 0; ni < 4; ++ni) {
#pragma unroll
        for (int r = 0; r < 4; ++r) {
          int lr = mi * 16 + rq + r;
          int row = m0 + wvM * 64 + lr;
          float v = acc[mi][ni][r] + bi[ni];
          if (RELU) v = fmaxf(v, 0.f);
          if (row < M) {
            stg[(lr - h * 32) * 64 + ni * 16 + fm] = (_Float16)v;
            if (STATS) { ssum[ni] += v; ssq[ni] += v * v; }
          }
        }
      }
    }
    if (bandc < NREAL) {
#pragma unroll
      for (int rr = 0; rr < 4; ++rr) {
        int lr = rr * 8 + rr0;
        int row = m0 + wvM * 64 + h * 32 + lr;
        if (row < M)
          *(f16x8*)&C[(size_t)row * ldC + bandc + c8] = *(const f16x8*)&stg[lr * 64 + c8];
      }
    }
  }
  if (STATS) {
    __syncthreads();
    float* sred = (float*)(((_Float16*)lds) + 8 * 2048);  // above the 32 KB staging region
    if (t < 128) { sred[t] = 0.f; sred[128 + t] = 0.f; }
    __syncthreads();
    const int wn = wvN * 64;
#pragma unroll
    for (int ni = 0; ni < 4; ++ni) {
      atomicAdd(&sred[wn + ni * 16 + fm], ssum[ni]);
      atomicAdd(&sred[128 + wn + ni * 16 + fm], ssq[ni]);
    }
    __syncthreads();
    if (t < 128) {
      // transposed per-M-tile partials: plain scattered stores, zero contention
      int gc = bx * 128 + t;
      partT[(size_t)gc * PT_LD + by] = sred[t];
      partT[(size_t)(EMB_G + gc) * PT_LD + by] = sred[128 + t];
    }
  }
}

// ---------------- reduce transposed partials: one wave per column, coalesced ----------------

__global__ __launch_bounds__(256) void stats_reduce_kernel(const float* __restrict__ partT,
                                                           float* __restrict__ stats) {
  int row = (blockIdx.x * 256 + threadIdx.x) >> 6;  // 0 .. 2*EMB_G-1 (grid 192 x 4 waves)
  int lane = threadIdx.x & 63;
  if (row >= 2 * EMB_G) return;
  float s = 0.f;
  for (int c = lane; c < MT256; c += 64) s += partT[(size_t)row * PT_LD + c];
#pragma unroll
  for (int o = 32; o > 0; o >>= 1) s += __shfl_down(s, o, 64);
  if (lane == 0) stats[row] = s;
}

// ---------------- readout ----------------

#define POOL_BLOCKS 784

__global__ __launch_bounds__(256) void pool2_kernel(const _Float16* __restrict__ h,
                                                    const int* __restrict__ gid,
                                                    float* __restrict__ graw) {
  const int w = (blockIdx.x * 256 + threadIdx.x) >> 6;
  const int lane = threadIdx.x & 63;
  const int NW = POOL_BLOCKS * 4;
  const int rpw = (NN + NW - 1) / NW;
  int r0 = w * rpw, r1 = min(r0 + rpw, NN);
  if (r0 >= r1 || lane >= 40) return;
  const f16x8* hb = (const f16x8*)h;
  float acc[8] = {};
  int curg = gid[r0];
  for (int r = r0; r < r1; ++r) {
    int g = gid[r];
    if (g != curg) {
#pragma unroll
      for (int i = 0; i < 8; ++i) {
        atomicAdd(&graw[curg * EMB_P + lane * 8 + i], acc[i]);
        acc[i] = 0.f;
      }
      curg = g;
    }
    f16x8 v = hb[(size_t)r * 40 + lane];
#pragma unroll
    for (int i = 0; i < 8; ++i) acc[i] += (float)v[i];
  }
#pragma unroll
  for (int i = 0; i < 8; ++i) atomicAdd(&graw[curg * EMB_P + lane * 8 + i], acc[i]);
}

__global__ void final_kernel(const float* __restrict__ graw, const int* __restrict__ gid,
                             const float* __restrict__ stats, const float* __restrict__ gamma,
                             const float* __restrict__ beta,
                             const float* __restrict__ wt, const float* __restrict__ bt,
                             float* __restrict__ out) {
  int g = blockIdx.x, t = threadIdx.x;  // 64 threads
  __shared__ int sb[2];
  __shared__ float scl[DEMB], shl[DEMB];
  for (int q = t; q < DEMB; q += 64) {
    float mu = stats[q] * (1.f / (float)NN);
    float var = fmaxf(stats[EMB_G + q] * (1.f / (float)NN) - mu * mu, 0.f);
    float s = gamma[q] * rsqrtf(var + BN_EPS_F);
    scl[q] = s;
    shl[q] = beta[q] - mu * s;
  }
  if (t < 2) {
    int target = g + t;
    int lo = 0, hi = NN;
    while (lo < hi) {
      int m = (lo + hi) >> 1;
      if (gid[m] < target) lo = m + 1; else hi = m;
    }
    sb[t] = lo;
  }
  __syncthreads();
  int cnt = sb[1] - sb[0];
  float inv = cnt > 0 ? 1.0f / (float)cnt : 0.f;
  float sh_on = cnt > 0 ? 1.0f : 0.f;
  float acc = bt[t];
  const float* row = graw + g * EMB_P;
  for (int k = 0; k < DEMB; ++k) {
    float gf = row[k] * inv * scl[k] + sh_on * shl[k];
    acc = fmaf(gf, wt[k * DOUT + t], acc);
  }
  out[g * DOUT + t] = acc;
}

// ---------------- launch ----------------

extern "C" void kernel_launch(void* const* d_in, const int* in_sizes, int n_in,
                              void* d_out, int out_size, void* d_ws, size_t ws_size,
                              hipStream_t stream) {
  const float* node_feats = (const float*)d_in[0];
  const float* edge_feats = (const float*)d_in[1];
  const int* src = (const int*)d_in[2];
  const int* dst = (const int*)d_in[3];
  const int* gid = (const int*)d_in[4];
  const float* w1_0 = (const float*)d_in[5];
  const float* b1_0 = (const float*)d_in[6];
  const float* w2_0 = (const float*)d_in[7];
  const float* b2_0 = (const float*)d_in[8];
  const float* gamma_0 = (const float*)d_in[9];
  const float* beta_0 = (const float*)d_in[10];
  const float* w1s = (const float*)d_in[11];
  const float* b1s = (const float*)d_in[12];
  const float* w2s = (const float*)d_in[13];
  const float* b2s = (const float*)d_in[14];
  const float* gammas = (const float*)d_in[15];
  const float* betas = (const float*)d_in[16];
  const float* wt = (const float*)d_in[17];
  const float* bt = (const float*)d_in[18];
  float* out = (float*)d_out;
  (void)in_sizes; (void)n_in; (void)out_size; (void)ws_size;

  char* ws = (char*)d_ws;
  size_t off = 0;
  auto carve = [&](size_t bytes) -> void* {
    void* p = ws + off;
    off += (bytes + 255) & ~(size_t)255;
    return p;
  };
  _Float16* P0 = (_Float16*)carve((size_t)NN * EMB_P * 2);   // agg (holds [N][32] for l0)
  _Float16* P1 = (_Float16*)carve((size_t)NN * EMB_P * 2);   // raw h2 (pre-BN)
  _Float16* Q  = (_Float16*)carve((size_t)NN * HID_P * 2);   // h1
  // zero-init region: packed, graw, stats contiguous -> ONE memset
  size_t zbeg = off;
  unsigned long long* packed = (unsigned long long*)carve((size_t)NN * 8);
  float* graw   = (float*)carve((size_t)NG * EMB_P * 4);
  float* stats  = (float*)carve((size_t)5 * 2 * EMB_G * 4);  // 5 per-layer regions
  size_t zend = off;
  float* esum   = (float*)carve((size_t)NN * 4);
  int* row_ptr  = (int*)carve((size_t)(NN + 1) * 4);
  int* csr_src  = (int*)carve((size_t)NE * 4);
  int* bsums    = (int*)carve((size_t)SCAN_BLK * 4);
  _Float16* w1t0 = (_Float16*)carve((size_t)HID_P * DIN_P * 2);
  _Float16* w1t  = (_Float16*)carve((size_t)4 * HID_P * EMB_P * 2);
  _Float16* w2t  = (_Float16*)carve((size_t)5 * EMB_G * HID_P * 2);
  float* b1p   = (float*)carve((size_t)5 * HID_P * 4);
  float* b2p   = (float*)carve((size_t)5 * EMB_G * 4);

  // nf32 (padded node_feats, fp32 [N][32] = 12.8 MB) ALIASES the start of Q:
  // consumed by spmm0 strictly before layer-0 gemm1 writes Q (same stream).
  float* nf32 = (float*)Q;
  // ord (per-edge ordinal, 6.4 MB) ALIASES Q at +16 MB: written by pass1,
  // consumed by place, both strictly before layer-0 gemm1 writes Q.
  unsigned* ord = (unsigned*)((char*)Q + (16u << 20));
  // partT (transposed stats partials, [2*EMB_G][PT_LD] f32 = 1.23 MB) ALIASES P0:
  // P0 is dead between gemm1(l) (last read) and spmm(l+1) (next write);
  // gemm2(l) writes partT, stats_reduce(l) reads it before spmm(l+1).
  float* partT = (float*)P0;

  hipMemsetAsync(ws + zbeg, 0, zend - zbeg, stream);

  // CSR by dst: one packed-atomic pass, scan (decodes esum), atomic-free placement
  pass1_kernel<<<(NE + 255) / 256, 256, 0, stream>>>(dst, edge_feats, packed, ord);
  scan_part1<<<SCAN_BLK, 256, 0, stream>>>(packed, bsums);
  scan_part3<<<SCAN_BLK, 256, 0, stream>>>(packed, bsums, row_ptr, esum);
  place_kernel<<<(NE + 255) / 256, 256, 0, stream>>>(src, dst, row_ptr, ord, csr_src);

  pad_nf_kernel<<<(NN * 32 + 255) / 256, 256, 0, stream>>>(node_feats, nf32);

  repack_all_kernel<<<(RT4 + 255) / 256, 256, 0, stream>>>(
      w1_0, w1s, w2_0, w2s, b1_0, b1s, b2_0, b2s, w1t0, w1t, w2t, b1p, b2p);

  const int MT = MT256;                      // 391 M-tiles (256-row)
  const int G8 = ((MT + 7) / 8) * 8;         // 392 (padded for XCD decode)
  const int spmm_half_blocks = (NN / 2) * 64 / 256;  // 12500
  const int spmm0_blocks = (NN * 32 + 255) / 256;

  for (int l = 0; l < 5; ++l) {
    const _Float16* w1t_l = (l == 0) ? w1t0 : w1t + (size_t)(l - 1) * HID_P * EMB_P;
    const _Float16* w2t_l = w2t + (size_t)l * EMB_G * HID_P;
    const float* b1p_l = b1p + (size_t)l * HID_P;
    const float* b2p_l = b2p + (size_t)l * EMB_G;
    float* stats_l = stats + (size_t)l * 2 * EMB_G;
    int K1 = (l == 0) ? DIN_P : EMB_P;

    if (l == 0) {
      spmm0_kernel<<<spmm0_blocks, 256, 0, stream>>>(nf32, row_ptr, csr_src, esum, P0);
    } else {
      const float* pg = (l == 1) ? gamma_0 : gammas + (size_t)(l - 2) * DEMB;
      const float* pb = (l == 1) ? beta_0 : betas + (size_t)(l - 2) * DEMB;
      const float* st = stats + (size_t)(l - 1) * 2 * EMB_G;
      spmm_f16_kernel<<<spmm_half_blocks, 256, 0, stream>>>(
          P1, st, pg, pb, row_ptr, csr_src, esum, P0, 0);
      spmm_f16_kernel<<<spmm_half_blocks, 256, 0, stream>>>(
          P1, st, pg, pb, row_ptr, csr_src, esum, P0, NN / 2);
    }

    gemm_pipe_kernel<true, false, 5><<<5 * G8, 512, 0, stream>>>(
        P0, w1t_l, b1p_l, Q, NN, K1, K1, HID_P, HID_P, MT, nullptr);

    // K trimmed 640 -> 608: cols 600..639 of Q and rows 600..639 of W2 are structurally zero
    gemm_pipe_kernel<false, true, 3><<<3 * G8, 512, 0, stream>>>(
        Q, w2t_l, b2p_l, P1, NN, 608, HID_P, EMB_P, EMB_P, MT, partT);

    stats_reduce_kernel<<<(2 * EMB_G + 3) / 4, 256, 0, stream>>>(partT, stats_l);
  }

  pool2_kernel<<<POOL_BLOCKS, 256, 0, stream>>>(P1, gid, graw);
  final_kernel<<<NG, 64, 0, stream>>>(graw, gid, stats + (size_t)4 * 2 * EMB_G,
                                      gammas + (size_t)3 * DEMB, betas + (size_t)3 * DEMB,
                                      wt, bt, out);
}